// Round 7
// baseline (275.394 us; speedup 1.0000x reference)
//
#include <hip/hip_runtime.h>
#include <stdint.h>

typedef __bf16 bf16;
typedef bf16 bf16x2 __attribute__((ext_vector_type(2)));
typedef bf16 bf16x4 __attribute__((ext_vector_type(4)));
typedef bf16 bf16x8 __attribute__((ext_vector_type(8)));
typedef float f32x4 __attribute__((ext_vector_type(4)));
typedef float f32x16 __attribute__((ext_vector_type(16)));

static constexpr int Bc = 4, Sc = 1024, Ec = 1024, Hc = 16, Dc = 64, BSc = 4096;

__device__ __forceinline__ void gld_lds16(const void* g, void* s) {
  __builtin_amdgcn_global_load_lds((const __attribute__((address_space(1))) void*)g,
                                   (__attribute__((address_space(3))) void*)s, 16, 0, 0);
}

// ---------------------------------------------------------------------------
// Mask element-stride detection (u8 vs 4-byte encodings) + allTrue init.
__global__ void detect_mask_kernel(const uint8_t* __restrict__ mask, int* flag) {
  if (threadIdx.x == 0 && blockIdx.x == 0) {
    bool everyGroupHasZero = true;
    bool anyNonzero = false;
    for (int j = 0; j < 16; ++j) {
      bool z = false;
      for (int bjj = 0; bjj < 4; ++bjj) {
        uint8_t byte = mask[4 * j + bjj];
        if (byte == 0) z = true;
        if (byte != 0) anyNonzero = true;
      }
      if (!z) everyGroupHasZero = false;
    }
    flag[0] = (everyGroupHasZero && anyNonzero) ? 4 : 1;
    flag[1] = 1;  // allTrue, refined by scan_mask_kernel
  }
}

// Full-mask scan: clears flag[1] if any element is false (deterministic).
__global__ __launch_bounds__(256) void scan_mask_kernel(const uint8_t* __restrict__ mask,
                                                        int* __restrict__ mflag) {
  const int stride = mflag[0];
  bool ok = true;
  const uint4* p = (const uint4*)mask;
  if (stride == 1) {
    const int n = (Bc * Sc * Sc) / 16;
    for (int i = blockIdx.x * blockDim.x + threadIdx.x; i < n; i += gridDim.x * blockDim.x) {
      uint4 w = p[i];
      uint32_t z = 0;
      z |= (w.x - 0x01010101u) & ~w.x;
      z |= (w.y - 0x01010101u) & ~w.y;
      z |= (w.z - 0x01010101u) & ~w.z;
      z |= (w.w - 0x01010101u) & ~w.w;
      if (z & 0x80808080u) ok = false;
    }
  } else {
    const int n = (Bc * Sc * Sc) / 4;
    for (int i = blockIdx.x * blockDim.x + threadIdx.x; i < n; i += gridDim.x * blockDim.x) {
      uint4 w = p[i];
      if (w.x == 0u || w.y == 0u || w.z == 0u || w.w == 0u) ok = false;
    }
  }
  if (!ok) atomicAnd(&mflag[1], 0);
}

// ---------------------------------------------------------------------------
// fp32 -> bf16 for query/key_/value (3 x 4M elements)
__global__ __launch_bounds__(256) void convert_x_kernel(
    const float* __restrict__ q, const float* __restrict__ k, const float* __restrict__ v,
    bf16* __restrict__ xb) {
  const int n4 = (BSc * Ec) / 4;
  for (int i = blockIdx.x * blockDim.x + threadIdx.x; i < 3 * n4; i += gridDim.x * blockDim.x) {
    int which = i / n4;
    int off = i - which * n4;
    const float4* src = (which == 0) ? (const float4*)q : (which == 1) ? (const float4*)k : (const float4*)v;
    float4 f = src[off];
    bf16x4 o;
    o[0] = (bf16)f.x; o[1] = (bf16)f.y; o[2] = (bf16)f.z; o[3] = (bf16)f.w;
    *(bf16x4*)(xb + (size_t)which * BSc * Ec + (size_t)off * 4) = o;
  }
}

// ---------------------------------------------------------------------------
// W [K][N] fp32 -> WT [N][K] bf16
__global__ __launch_bounds__(256) void convtrans_w_kernel(
    const float* __restrict__ Wq, const float* __restrict__ Wk,
    const float* __restrict__ Wv, const float* __restrict__ Wo,
    bf16* __restrict__ wT) {
  __shared__ float tile[64][65];
  const int k0 = blockIdx.x * 64, n0 = blockIdx.y * 64, z = blockIdx.z;
  const float* W = (z == 0) ? Wq : (z == 1) ? Wk : (z == 2) ? Wv : Wo;
  bf16* out = wT + (size_t)z * Ec * Ec;
  const int t = threadIdx.x;
#pragma unroll
  for (int p = 0; p < 16; p++) {
    int r = p * 4 + (t >> 6), c = t & 63;
    tile[r][c] = W[(size_t)(k0 + r) * Ec + n0 + c];
  }
  __syncthreads();
#pragma unroll
  for (int p = 0; p < 8; p++) {
    int n = p * 8 + (t >> 5), kk = (t & 31) * 2;
    bf16x2 v2;
    v2[0] = (bf16)tile[kk][n];
    v2[1] = (bf16)tile[kk + 1][n];
    *(bf16x2*)(out + (size_t)(n0 + n) * Ec + k0 + kk) = v2;
  }
}

// ---------------------------------------------------------------------------
// 128x128-tile bf16 GEMM. MODE 0: fp32 [M][N] out. MODE 1: bf16 head-split
// [B,H,S,D] out; z==0 (Q) pre-scaled by 1/sqrt(D)=0.125 (exact pow2).
template <int MODE>
__global__ __launch_bounds__(256) void gemm128_kernel(
    const bf16* __restrict__ A_, const bf16* __restrict__ W_,
    const float* __restrict__ bias0, const float* __restrict__ bias1, const float* __restrict__ bias2,
    bf16* __restrict__ outb_, float* __restrict__ outf) {
  constexpr int K = 1024, N = 1024;
  const int z = blockIdx.z;
  const bf16* A = A_ + (size_t)z * BSc * K;
  const bf16* Wt = W_ + (size_t)z * N * K;
  const float* bias = (z == 0) ? bias0 : (z == 1) ? bias1 : bias2;
  bf16* outb = outb_ + (size_t)z * Bc * Hc * Sc * Dc;
  const float oscale = (MODE == 1 && z == 0) ? 0.125f : 1.0f;
  const int n0 = blockIdx.x * 128, m0 = blockIdx.y * 128;

  __shared__ bf16 As[128 * 64];
  __shared__ bf16 Bs[128 * 64];
  const int t = threadIdx.x, wave = t >> 6, lane = t & 63;
  const int wr = wave >> 1, wc = wave & 1;

  f32x4 acc[4][4];
#pragma unroll
  for (int i = 0; i < 4; i++)
#pragma unroll
    for (int j = 0; j < 4; j++)
#pragma unroll
      for (int r = 0; r < 4; r++) acc[i][j][r] = 0.f;

  const int srow = (lane >> 3);
  const int scol = (lane & 7) * 8;

  for (int kt = 0; kt < K; kt += 64) {
#pragma unroll
    for (int i = 0; i < 4; i++) {
      const int chunk = i * 4 + wave;
      const int row = chunk * 8 + srow;
      gld_lds16(A + (size_t)(m0 + row) * K + kt + scol, &As[chunk * 512]);
      gld_lds16(Wt + (size_t)(n0 + row) * K + kt + scol, &Bs[chunk * 512]);
    }
    __syncthreads();
#pragma unroll
    for (int kk = 0; kk < 2; kk++) {
      bf16x8 af[4], bg[4];
#pragma unroll
      for (int i = 0; i < 4; i++) {
        af[i] = *(const bf16x8*)&As[(64 * wr + i * 16 + (lane & 15)) * 64 + kk * 32 + (lane >> 4) * 8];
        bg[i] = *(const bf16x8*)&Bs[(64 * wc + i * 16 + (lane & 15)) * 64 + kk * 32 + (lane >> 4) * 8];
      }
#pragma unroll
      for (int mi = 0; mi < 4; mi++)
#pragma unroll
        for (int ni = 0; ni < 4; ni++)
          acc[mi][ni] = __builtin_amdgcn_mfma_f32_16x16x32_bf16(af[mi], bg[ni], acc[mi][ni], 0, 0, 0);
    }
    __syncthreads();
  }

#pragma unroll
  for (int mi = 0; mi < 4; mi++) {
#pragma unroll
    for (int ni = 0; ni < 4; ni++) {
      const int col = n0 + 64 * wc + ni * 16 + (lane & 15);
      const float bvl = bias[col];
#pragma unroll
      for (int r = 0; r < 4; r++) {
        const int row = m0 + 64 * wr + mi * 16 + (lane >> 4) * 4 + r;
        const float v = (acc[mi][ni][r] + bvl) * oscale;
        if (MODE == 0) {
          outf[(size_t)row * N + col] = v;
        } else {
          const int bidx = row >> 10, s = row & 1023, hh = col >> 6, d = col & 63;
          outb[(((size_t)bidx * Hc + hh) * Sc + s) * Dc + d] = (bf16)v;
        }
      }
    }
  }
}

// ---------------------------------------------------------------------------
// V [bh][S][D] -> VT [bh][D][S] (bf16)
__global__ __launch_bounds__(256) void transpose_v_kernel(const bf16* __restrict__ Vb,
                                                          bf16* __restrict__ VTb) {
  __shared__ bf16 tile[64][66];
  const int s0 = blockIdx.x * 64, bh = blockIdx.y;
  const bf16* src = Vb + (size_t)bh * Sc * Dc;
  bf16* dst = VTb + (size_t)bh * Dc * Sc;
  const int t = threadIdx.x;
#pragma unroll
  for (int p = 0; p < 8; p++) {
    int s = p * 8 + (t >> 5), d = (t & 31) * 2;
    *(bf16x2*)&tile[s][d] = *(const bf16x2*)(src + (size_t)(s0 + s) * Dc + d);
  }
  __syncthreads();
#pragma unroll
  for (int p = 0; p < 8; p++) {
    int d = p * 8 + (t >> 5), s = (t & 31) * 2;
    bf16x2 v2;
    v2[0] = tile[s][d];
    v2[1] = tile[s + 1][d];
    *(bf16x2*)(dst + (size_t)d * Sc + s0 + s) = v2;
  }
}

// ---------------------------------------------------------------------------
// One 32k x 32q score tile D[k][q] at k-base `kt`, masked. Lane holds col
// q=q0+l31; rows (reg&3)+8*(reg>>2)+4*hi. Bit-identical to the r3-r5
// validated QK code.
__device__ __forceinline__ f32x16 qk_tile(const bf16* __restrict__ Kbh, const bf16x8 qf[4],
                                          int kt, const uint8_t* __restrict__ mrow1,
                                          const uint8_t* __restrict__ mrow4,
                                          int allTrue, int l31, int hi) {
  const bf16* Kp = Kbh + (size_t)(kt + l31) * Dc;
  f32x16 a;
#pragma unroll
  for (int r = 0; r < 16; r++) a[r] = 0.f;
#pragma unroll
  for (int ks = 0; ks < 4; ks++) {
    bf16x8 kf = *(const bf16x8*)(Kp + ks * 16 + hi * 8);
    a = __builtin_amdgcn_mfma_f32_32x32x16_bf16(kf, qf[ks], a, 0, 0, 0);
  }
  if (!allTrue) {
    if (mrow4 == nullptr) {
#pragma unroll
      for (int g = 0; g < 4; g++) {
        const int kg = kt + g * 8 + hi * 4;
        const uint32_t mw = *(const uint32_t*)(mrow1 + kg);
#pragma unroll
        for (int r = 0; r < 4; r++)
          if (((mw >> (8 * r)) & 0xffu) == 0u) a[g * 4 + r] = -1e9f;
      }
    } else {
#pragma unroll
      for (int g = 0; g < 4; g++) {
        const int kg = kt + g * 8 + hi * 4;
        const uint4 m4 = *(const uint4*)(mrow4 + (size_t)4 * kg);
        const uint32_t w[4] = {m4.x, m4.y, m4.z, m4.w};
#pragma unroll
        for (int r = 0; r < 4; r++)
          if (w[r] == 0u) a[g * 4 + r] = -1e9f;
      }
    }
  }
  return a;
}

// ---------------------------------------------------------------------------
// Fused attention v5: WAVE-LOCAL 3-pass, zero barriers. Each wave owns 32
// q-rows x ALL 1024 k (grid 8x16x4, 4 waves/WG; qblk = bx*4+wave). Softmax
// state (M, L) lives in registers; no cross-wave or cross-kernel plumbing.
//   pass A: M = max_k score      (order-free max — trivially correct)
//   pass B: L = sum exp(s - M)   (fixed M, plain accumulation)
//   pass C: recompute QK, P=exp(s-M)/L -> per-wave LDS tile -> dense
//           nontemporal weights stores + PV (r5-validated tile code),
//           then ctx densified through the same LDS tile.
__global__ __launch_bounds__(256) void attn_kernel(
    const bf16* __restrict__ Qb, const bf16* __restrict__ Kb, const bf16* __restrict__ VTb,
    const uint8_t* __restrict__ mask, const int* __restrict__ mflag,
    float* __restrict__ wout_, bf16* __restrict__ ctx) {
  const int h = blockIdx.y, b = blockIdx.z;
  const int bh = b * Hc + h;
  const int t = threadIdx.x, wave = t >> 6, lane = t & 63;
  const int l31 = lane & 31, hi = lane >> 5;
  const int qblk = blockIdx.x * 4 + wave;
  const int q0 = qblk * 32, q = q0 + l31;

  __shared__ float pool[4][32 * 33];  // per-wave P tile, wave-private
  float* Pt = pool[wave];

  const bf16* Qp = Qb + ((size_t)bh * Sc + q) * Dc;
  bf16x8 qf[4];
#pragma unroll
  for (int ks = 0; ks < 4; ks++) qf[ks] = *(const bf16x8*)(Qp + ks * 16 + hi * 8);

  const int allTrue = mflag[1];
  const int mstride = mflag[0];
  const uint8_t* mrow1 = mask + (size_t)(b * Sc + q) * Sc;
  const uint8_t* mrow4 = (mstride == 4) ? mask + (size_t)(b * Sc + q) * Sc * 4 : nullptr;
  const bf16* Kbh = Kb + (size_t)bh * Sc * Dc;

  // ---- pass A: row max over all k
  float mx = -3.0e38f;
  for (int kt = 0; kt < Sc; kt += 32) {
    const f32x16 a = qk_tile(Kbh, qf, kt, mrow1, mrow4, allTrue, l31, hi);
#pragma unroll
    for (int r = 0; r < 16; r++) mx = fmaxf(mx, a[r]);
  }
  mx = fmaxf(mx, __shfl_xor(mx, 32));

  // ---- pass B: denominator with fixed M
  float ls = 0.f;
  for (int kt = 0; kt < Sc; kt += 32) {
    const f32x16 a = qk_tile(Kbh, qf, kt, mrow1, mrow4, allTrue, l31, hi);
#pragma unroll
    for (int r = 0; r < 16; r++) ls += __expf(a[r] - mx);
  }
  ls += __shfl_xor(ls, 32);
  const float invl = 1.f / ls;

  // ---- pass C: P -> LDS -> dense weights stores + PV
  const bf16* VTbh = VTb + (size_t)bh * Dc * Sc;
  float* wbase = wout_ + ((size_t)bh * Sc + q0) * Sc;
  f32x16 oacc[2];
#pragma unroll
  for (int nj = 0; nj < 2; nj++)
#pragma unroll
    for (int r = 0; r < 16; r++) oacc[nj][r] = 0.f;

  for (int kt = 0; kt < Sc; kt += 32) {
    const f32x16 a = qk_tile(Kbh, qf, kt, mrow1, mrow4, allTrue, l31, hi);
    // P[q=l31][k-local = 8g+4hi+r] = exp(a-M)*invl
#pragma unroll
    for (int g = 0; g < 4; g++) {
      f32x4 w4;
#pragma unroll
      for (int r = 0; r < 4; r++) w4[r] = __expf(a[g * 4 + r] - mx) * invl;
      *(f32x4*)&Pt[l31 * 33 + g * 8 + hi * 4] = w4;
    }
    // dense weights stores: 4 instrs x (8 rows x 128B), nontemporal
#pragma unroll
    for (int i = 0; i < 4; i++) {
      const int q2 = 8 * i + (lane >> 3), kk = (lane & 7) * 4;
      const f32x4 v4 = *(const f32x4*)&Pt[q2 * 33 + kk];
      __builtin_nontemporal_store(v4, (f32x4*)(wbase + (size_t)q2 * Sc + kt + kk));
    }
    // PV: pa from Pt, bv from VT; accumulate O[q][d]
#pragma unroll
    for (int st = 0; st < 2; st++) {
      const f32x4 a0 = *(const f32x4*)&Pt[l31 * 33 + st * 16 + hi * 8];
      const f32x4 a1 = *(const f32x4*)&Pt[l31 * 33 + st * 16 + hi * 8 + 4];
      bf16x8 pa;
#pragma unroll
      for (int j = 0; j < 4; j++) {
        pa[j] = (bf16)a0[j];
        pa[4 + j] = (bf16)a1[j];
      }
#pragma unroll
      for (int nj = 0; nj < 2; nj++) {
        const bf16x8 bv = *(const bf16x8*)(VTbh + (size_t)(nj * 32 + l31) * Sc + kt + st * 16 + hi * 8);
        oacc[nj] = __builtin_amdgcn_mfma_f32_32x32x16_bf16(pa, bv, oacc[nj], 0, 0, 0);
      }
    }
  }

  // ---- ctx write, densified per 32d-half through the wave-private Pt
  // (in-wave LDS write->read ordering; no barriers needed)
#pragma unroll
  for (int nj = 0; nj < 2; nj++) {
#pragma unroll
    for (int rg = 0; rg < 16; rg++) {
      const int qq = (rg & 3) + 8 * (rg >> 2) + 4 * hi;
      Pt[qq * 33 + l31] = oacc[nj][rg];
    }
    const int rr = lane >> 1, c0 = (lane & 1) * 16;
    bf16x8 o0, o1;
#pragma unroll
    for (int j = 0; j < 8; j++) {
      o0[j] = (bf16)Pt[rr * 33 + c0 + j];
      o1[j] = (bf16)Pt[rr * 33 + c0 + 8 + j];
    }
    bf16* cbase = ctx + ((size_t)(b * Sc + q0 + rr)) * Ec + h * Dc + nj * 32 + c0;
    *(bf16x8*)cbase = o0;
    *(bf16x8*)(cbase + 8) = o1;
  }
}

// ---------------------------------------------------------------------------
extern "C" void kernel_launch(void* const* d_in, const int* in_sizes, int n_in,
                              void* d_out, int out_size, void* d_ws, size_t ws_size,
                              hipStream_t stream) {
  const float* q = (const float*)d_in[0];
  const float* k = (const float*)d_in[1];
  const float* v = (const float*)d_in[2];
  const uint8_t* mask = (const uint8_t*)d_in[3];
  const float* Wq = (const float*)d_in[4];
  const float* bq = (const float*)d_in[5];
  const float* Wk = (const float*)d_in[6];
  const float* bk = (const float*)d_in[7];
  const float* Wv = (const float*)d_in[8];
  const float* bv = (const float*)d_in[9];
  const float* Wo = (const float*)d_in[10];
  const float* bo = (const float*)d_in[11];

  // Workspace (bf16 elems): [0,4M) xb.q -> ctx; [4M,8M) xb.k -> VTb;
  // [8M,12M) xb.v; [12,16M) wT; [16,28M) Qb/Kb/Vb; byte 56MB: mflag.
  bf16* wsb = (bf16*)d_ws;
  bf16* xb = wsb;
  bf16* ctx = wsb;
  bf16* VTb = wsb + (size_t)4 * 1024 * 1024;
  bf16* wT = wsb + (size_t)12 * 1024 * 1024;
  bf16* Qb = wsb + (size_t)16 * 1024 * 1024;
  bf16* Kb = wsb + (size_t)20 * 1024 * 1024;
  bf16* Vb = wsb + (size_t)24 * 1024 * 1024;
  int* mflag = (int*)((char*)d_ws + (size_t)56 * 1024 * 1024);

  float* outf = (float*)d_out;
  float* attnw = outf + (size_t)4 * 1024 * 1024;

  detect_mask_kernel<<<1, 64, 0, stream>>>(mask, mflag);
  scan_mask_kernel<<<1024, 256, 0, stream>>>(mask, mflag);
  convert_x_kernel<<<2048, 256, 0, stream>>>(q, k, v, xb);
  convtrans_w_kernel<<<dim3(16, 16, 4), 256, 0, stream>>>(Wq, Wk, Wv, Wo, wT);
  gemm128_kernel<1><<<dim3(8, 32, 3), 256, 0, stream>>>(xb, wT, bq, bk, bv, Qb, nullptr);
  transpose_v_kernel<<<dim3(16, 64), 256, 0, stream>>>(Vb, VTb);
  attn_kernel<<<dim3(8, 16, 4), 256, 0, stream>>>(Qb, Kb, VTb, mask, mflag, attnw, ctx);
  gemm128_kernel<0><<<dim3(8, 32, 1), 256, 0, stream>>>(ctx, wT + (size_t)3 * 1024 * 1024,
                                                        bo, bo, bo, nullptr, outf);
}